// Round 6
// baseline (191.000 us; speedup 1.0000x reference)
//
#include <hip/hip_runtime.h>
#include <hip/hip_bf16.h>

#define BATCH 512
#define SEQL  512
#define NCH   14
#define NCLS  5
#define DPAD  128          // padded emb dim (d=100..127 zeros)
#define KSTEPS 20          // K = 5*128 / 32
#define POSB  64           // positions per block
#define ROWS  68           // POSB + 4 halo
#define BLKS_PER_ROW 8
#define NBLK  (BATCH * BLKS_PER_ROW)
#define WS_B_BYTES 20480   // 20 ksteps * 64 lanes * 16 B  (B fragments, bf16)
#define BIAS_OFF   20480   // f32[16]
#define FEAT_OFF   20544   // f32[NBLK*16] = 262144 B
#define CTR_OFF    282688  // int[BATCH]
#define NIT   9            // ceil(ROWS*32 / 256) staging iterations

typedef __attribute__((ext_vector_type(8))) short bf16x8;
typedef __attribute__((ext_vector_type(4))) float f32x4;

static __device__ __forceinline__ unsigned short bf16bits(float f) {
    __hip_bfloat16 h = __float2bfloat16(f);
    return __builtin_bit_cast(unsigned short, h);
}

// ---------------- repack: conv weights -> MFMA B-fragment layout (bf16) + biases,
// and zero the per-row completion counters (must run before cnn_mfma each call).
__global__ void repack_w(
    const float* __restrict__ w2, const float* __restrict__ b2,
    const float* __restrict__ w3, const float* __restrict__ b3,
    const float* __restrict__ w4, const float* __restrict__ b4,
    const float* __restrict__ w5, const float* __restrict__ b5,
    unsigned short* __restrict__ wsb, float* __restrict__ biasf,
    int* __restrict__ ctr)
{
    const float* WP[4] = {w2, w3, w4, w5};
    const int gi = blockIdx.x * 256 + threadIdx.x;
    if (gi < WS_B_BYTES / 2) {
        int kstep = gi >> 9;         // / (64*8)
        int rem   = gi & 511;
        int l     = rem >> 3;
        int e     = rem & 7;
        int k     = kstep * 32 + ((l >> 4) << 3) + e;
        int n     = l & 15;
        int j     = k >> 7;          // tap
        int d     = k & 127;         // emb dim
        float v = 0.f;
        if (n < NCH && d < 100) {
            int kc = 2 + (n >= 2) + (n >= 5) + (n >= 9);
            if (j < kc) {
                int grp = (n >= 2) + (n >= 5) + (n >= 9);
                int ob  = (grp == 0) ? 0 : (grp == 1) ? 2 : (grp == 2) ? 5 : 9;
                v = WP[grp][((n - ob) * 100 + d) * kc + j];
            }
        }
        wsb[gi] = bf16bits(v);
    }
    if (gi < BATCH) ctr[gi] = 0;
    if (blockIdx.x == 0 && threadIdx.x < 16) {
        const int t = threadIdx.x;
        float bv = 0.f;
        if (t < 2)        bv = b2[t];
        else if (t < 5)   bv = b3[t - 2];
        else if (t < 9)   bv = b4[t - 5];
        else if (t < NCH) bv = b5[t - 9];
        biasf[t] = bv;
    }
}

// ---------------- main: 4096 blocks = 8 per batch row, 256 threads (4 waves)
// Stage X[68][128] bf16 into LDS (XOR-swizzled), MFMA 16x16x32 over K=640,
// fused bias+relu+masked max; last block per row max-combines + FC -> out.
__global__ __launch_bounds__(256, 8) void cnn_mfma(
    const int* __restrict__ words,
    const float* __restrict__ emb,
    const char* __restrict__ ws,
    float* __restrict__ feats,
    int* __restrict__ ctr,
    const float* __restrict__ fcw, const float* __restrict__ fcb,
    float* __restrict__ out)
{
    __shared__ unsigned short xs[ROWS * DPAD];   // 17408 B, swizzled
    __shared__ float red[4][16];
    __shared__ float ffin[16];
    __shared__ int lastFlag;

    const int bid = blockIdx.x;
    const int b   = bid >> 3;
    const int blk = bid & 7;
    const int p0  = blk * POSB;
    const int tid = threadIdx.x;
    const int l   = tid & 63;
    const int wv  = tid >> 6;

    // ---- phase 1: prefetch all token indices (one latency round) ----
    int toks[NIT];
    #pragma unroll
    for (int it = 0; it < NIT; ++it) {
        const int i = tid + it * 256;
        const int r = i >> 5;
        const int t = p0 + r;
        toks[it] = (i < ROWS * 32 && t < SEQL) ? words[b * SEQL + t] : -1;
    }

    // ---- phase 2: 9 independent row-chunk gathers -> swizzled LDS ----
    const float4* __restrict__ emb4 = reinterpret_cast<const float4*>(emb);
    uint2* xs2 = reinterpret_cast<uint2*>(xs);
    #pragma unroll
    for (int it = 0; it < NIT; ++it) {
        const int i = tid + it * 256;
        if (i < ROWS * 32) {
            const int r = i >> 5;
            const int q = i & 31;
            uint lo = 0, hi = 0;
            if (toks[it] >= 0 && q < 25) {
                float4 x = emb4[(long)toks[it] * 25 + q];
                lo = (uint)bf16bits(x.x) | ((uint)bf16bits(x.y) << 16);
                hi = (uint)bf16bits(x.z) | ((uint)bf16bits(x.w) << 16);
            }
            const int addr = (r * 256 + q * 8) ^ ((r & 7) << 4);
            xs2[addr >> 3] = make_uint2(lo, hi);   // zeros pad d>=100 & dead rows
        }
    }
    __syncthreads();

    // ---- MFMA: wave computes 16 positions x 16 channels, K=640 ----
    f32x4 acc = {0.f, 0.f, 0.f, 0.f};
    const int m0 = wv * 16 + (l & 15);
    const int dl = (l >> 4) << 3;                // k-slice d-offset: 0,8,16,24
    const char* xsb = reinterpret_cast<const char*>(xs);
    #pragma unroll
    for (int ks = 0; ks < KSTEPS; ++ks) {
        const int j  = ks >> 2;
        const int d0 = ((ks & 3) << 5) + dl;
        const int row = m0 + j;
        const int aad = (row * 256 + d0 * 2) ^ ((row & 7) << 4);
        bf16x8 a = *reinterpret_cast<const bf16x8*>(xsb + aad);
        bf16x8 bf = *reinterpret_cast<const bf16x8*>(ws + (ks * 64 + l) * 16);
        acc = __builtin_amdgcn_mfma_f32_16x16x32_bf16(a, bf, acc, 0, 0, 0);
    }

    // ---- bias + relu + masked max over this wave's 4 (pos-group) rows ----
    const int ch  = l & 15;
    const int kch = 2 + (ch >= 2) + (ch >= 5) + (ch >= 9);
    const float bias = *reinterpret_cast<const float*>(ws + BIAS_OFF + ch * 4);
    const int rbase = (l >> 4) << 2;
    float v = 0.f;
    #pragma unroll
    for (int r = 0; r < 4; ++r) {
        const int t = p0 + wv * 16 + rbase + r;       // C row = (lane>>4)*4+reg
        if (t + kch <= SEQL) v = fmaxf(v, fmaxf(acc[r] + bias, 0.f));
    }
    v = fmaxf(v, __shfl_xor(v, 16, 64));
    v = fmaxf(v, __shfl_xor(v, 32, 64));
    if (l < 16) red[wv][ch] = v;
    __syncthreads();

    if (tid < 16) {
        float f = fmaxf(fmaxf(red[0][tid], red[1][tid]),
                        fmaxf(red[2][tid], red[3][tid]));
        feats[bid * 16 + tid] = f;
    }
    // __syncthreads below (compiler drains vmcnt before s_barrier) ensures the
    // feats stores above have reached this XCD's L2 before the release fence.
    __syncthreads();

    // ---- last-block-per-row: combine 8 partials + FC (standard pattern) ----
    if (tid == 0) {
        __threadfence();                               // release: flush L2
        int old = atomicAdd(&ctr[b], 1);               // device-scope (m20)
        int last = (old == BLKS_PER_ROW - 1);
        if (last) __threadfence();                     // acquire: invalidate
        lastFlag = last;
    }
    __syncthreads();
    if (lastFlag) {
        const float* fb = feats + b * (16 * BLKS_PER_ROW);
        if (tid < 16) {
            float f = fb[tid];
            #pragma unroll
            for (int w = 1; w < BLKS_PER_ROW; ++w) f = fmaxf(f, fb[w * 16 + tid]);
            ffin[tid] = f;
        }
        __syncthreads();
        if (tid < NCLS) {
            float acc2 = fcb[tid];
            #pragma unroll
            for (int o = 0; o < NCH; ++o) acc2 += fcw[tid * NCH + o] * ffin[o];
            out[b * NCLS + tid] = acc2;
        }
    }
}

extern "C" void kernel_launch(void* const* d_in, const int* in_sizes, int n_in,
                              void* d_out, int out_size, void* d_ws, size_t ws_size,
                              hipStream_t stream) {
    const int*   words = (const int*)  d_in[0];
    const float* emb   = (const float*)d_in[1];
    const float* w2    = (const float*)d_in[2];
    const float* b2    = (const float*)d_in[3];
    const float* w3    = (const float*)d_in[4];
    const float* b3    = (const float*)d_in[5];
    const float* w4    = (const float*)d_in[6];
    const float* b4    = (const float*)d_in[7];
    const float* w5    = (const float*)d_in[8];
    const float* b5    = (const float*)d_in[9];
    const float* fcw   = (const float*)d_in[10];
    const float* fcb   = (const float*)d_in[11];
    float* out = (float*)d_out;
    char*  ws  = (char*)d_ws;

    unsigned short* wsb  = (unsigned short*)ws;
    float* biasf = (float*)(ws + BIAS_OFF);
    float* feats = (float*)(ws + FEAT_OFF);
    int*   ctr   = (int*)(ws + CTR_OFF);

    hipLaunchKernelGGL(repack_w, dim3(40), dim3(256), 0, stream,
                       w2, b2, w3, b3, w4, b4, w5, b5, wsb, biasf, ctr);
    hipLaunchKernelGGL(cnn_mfma, dim3(NBLK), dim3(256), 0, stream,
                       words, emb, ws, feats, ctr, fcw, fcb, out);
}

// Round 7
// 39.715 us; speedup vs baseline: 4.8093x; 4.8093x over previous
//
#include <hip/hip_runtime.h>
#include <hip/hip_bf16.h>

#define BATCH 512
#define SEQL  512
#define NCH   14
#define NCLS  5
#define DPAD  128          // padded emb dim (d=100..127 zeros)
#define KSTEPS 20          // K = 5*128 / 32
#define POSB  64           // positions per block
#define ROWS  68           // POSB + 4 halo
#define BLKS_PER_ROW 8
#define NBLK  (BATCH * BLKS_PER_ROW)
#define WS_B_BYTES 20480   // 20 ksteps * 64 lanes * 16 B  (B fragments, bf16)
#define BIAS_OFF   20480   // f32[16]
#define FEAT_OFF   20544   // f32[NBLK*16] = 262144 B
#define NIT   9            // ceil(ROWS*32 / 256) staging iterations

typedef __attribute__((ext_vector_type(8))) short bf16x8;
typedef __attribute__((ext_vector_type(4))) float f32x4;

static __device__ __forceinline__ unsigned short bf16bits(float f) {
    __hip_bfloat16 h = __float2bfloat16(f);
    return __builtin_bit_cast(unsigned short, h);
}

// ---------------- repack: conv weights -> MFMA B-fragment layout (bf16) + biases
__global__ void repack_w(
    const float* __restrict__ w2, const float* __restrict__ b2,
    const float* __restrict__ w3, const float* __restrict__ b3,
    const float* __restrict__ w4, const float* __restrict__ b4,
    const float* __restrict__ w5, const float* __restrict__ b5,
    unsigned short* __restrict__ wsb, float* __restrict__ biasf)
{
    const float* WP[4] = {w2, w3, w4, w5};
    const int gi = blockIdx.x * 256 + threadIdx.x;
    if (gi < WS_B_BYTES / 2) {
        int kstep = gi >> 9;         // / (64*8)
        int rem   = gi & 511;
        int l     = rem >> 3;
        int e     = rem & 7;
        int k     = kstep * 32 + ((l >> 4) << 3) + e;
        int n     = l & 15;
        int j     = k >> 7;          // tap
        int d     = k & 127;         // emb dim
        float v = 0.f;
        if (n < NCH && d < 100) {
            int kc = 2 + (n >= 2) + (n >= 5) + (n >= 9);
            if (j < kc) {
                int grp = (n >= 2) + (n >= 5) + (n >= 9);
                int ob  = (grp == 0) ? 0 : (grp == 1) ? 2 : (grp == 2) ? 5 : 9;
                v = WP[grp][((n - ob) * 100 + d) * kc + j];
            }
        }
        wsb[gi] = bf16bits(v);
    }
    if (blockIdx.x == 0 && threadIdx.x < 16) {
        const int t = threadIdx.x;
        float bv = 0.f;
        if (t < 2)        bv = b2[t];
        else if (t < 5)   bv = b3[t - 2];
        else if (t < 9)   bv = b4[t - 5];
        else if (t < NCH) bv = b5[t - 9];
        biasf[t] = bv;
    }
}

// ---------------- main: 4096 blocks = 8 per batch row, 256 threads (4 waves)
// Phase-split staging: (1) all token indices -> regs, (2) 9 independent
// gathers -> swizzled LDS. MFMA 16x16x32 over K=640, fused bias+relu+max.
__global__ __launch_bounds__(256, 8) void cnn_mfma(
    const int* __restrict__ words,
    const float* __restrict__ emb,
    const char* __restrict__ ws,
    float* __restrict__ feats)
{
    __shared__ unsigned short xs[ROWS * DPAD];   // 17408 B, swizzled
    __shared__ float red[4][16];

    const int bid = blockIdx.x;
    const int b   = bid >> 3;
    const int blk = bid & 7;
    const int p0  = blk * POSB;
    const int tid = threadIdx.x;
    const int l   = tid & 63;
    const int wv  = tid >> 6;

    // ---- phase 1: prefetch all token indices (one latency round) ----
    int toks[NIT];
    #pragma unroll
    for (int it = 0; it < NIT; ++it) {
        const int i = tid + it * 256;
        const int r = i >> 5;
        const int t = p0 + r;
        toks[it] = (i < ROWS * 32 && t < SEQL) ? words[b * SEQL + t] : -1;
    }

    // ---- phase 2: 9 independent row-chunk gathers -> swizzled LDS ----
    const float4* __restrict__ emb4 = reinterpret_cast<const float4*>(emb);
    uint2* xs2 = reinterpret_cast<uint2*>(xs);
    #pragma unroll
    for (int it = 0; it < NIT; ++it) {
        const int i = tid + it * 256;
        if (i < ROWS * 32) {
            const int r = i >> 5;
            const int q = i & 31;
            uint lo = 0, hi = 0;
            if (toks[it] >= 0 && q < 25) {
                float4 x = emb4[(long)toks[it] * 25 + q];
                lo = (uint)bf16bits(x.x) | ((uint)bf16bits(x.y) << 16);
                hi = (uint)bf16bits(x.z) | ((uint)bf16bits(x.w) << 16);
            }
            const int addr = (r * 256 + q * 8) ^ ((r & 7) << 4);
            xs2[addr >> 3] = make_uint2(lo, hi);   // zeros pad d>=100 & dead rows
        }
    }
    __syncthreads();

    // ---- MFMA: wave computes 16 positions x 16 channels, K=640 ----
    f32x4 acc = {0.f, 0.f, 0.f, 0.f};
    const int m0 = wv * 16 + (l & 15);
    const int dl = (l >> 4) << 3;                // k-slice d-offset: 0,8,16,24
    const char* xsb = reinterpret_cast<const char*>(xs);
    #pragma unroll
    for (int ks = 0; ks < KSTEPS; ++ks) {
        const int j  = ks >> 2;
        const int d0 = ((ks & 3) << 5) + dl;
        const int row = m0 + j;
        const int aad = (row * 256 + d0 * 2) ^ ((row & 7) << 4);
        bf16x8 a = *reinterpret_cast<const bf16x8*>(xsb + aad);
        bf16x8 bf = *reinterpret_cast<const bf16x8*>(ws + (ks * 64 + l) * 16);
        acc = __builtin_amdgcn_mfma_f32_16x16x32_bf16(a, bf, acc, 0, 0, 0);
    }

    // ---- bias + relu + masked max over this wave's 4 (pos-group) rows ----
    const int ch  = l & 15;
    const int kch = 2 + (ch >= 2) + (ch >= 5) + (ch >= 9);
    const float bias = *reinterpret_cast<const float*>(ws + BIAS_OFF + ch * 4);
    const int rbase = (l >> 4) << 2;
    float v = 0.f;
    #pragma unroll
    for (int r = 0; r < 4; ++r) {
        const int t = p0 + wv * 16 + rbase + r;       // C row = (lane>>4)*4+reg
        if (t + kch <= SEQL) v = fmaxf(v, fmaxf(acc[r] + bias, 0.f));
    }
    v = fmaxf(v, __shfl_xor(v, 16, 64));
    v = fmaxf(v, __shfl_xor(v, 32, 64));
    if (l < 16) red[wv][ch] = v;
    __syncthreads();

    if (tid < 16) {
        float f = fmaxf(fmaxf(red[0][tid], red[1][tid]),
                        fmaxf(red[2][tid], red[3][tid]));
        feats[bid * 16 + tid] = f;
    }
}

// ---------------- FC: combine 8 block-partials per row, tiny GEMV
__global__ void fc_kernel(const float* __restrict__ feats,
                          const float* __restrict__ fcw,
                          const float* __restrict__ fcb,
                          float* __restrict__ out)
{
    const int i = blockIdx.x * 256 + threadIdx.x;
    if (i >= BATCH * NCLS) return;
    const int b   = i / NCLS;
    const int cls = i - b * NCLS;
    const float* fb = feats + b * (16 * BLKS_PER_ROW);
    float acc = fcb[cls];
    #pragma unroll
    for (int o = 0; o < NCH; ++o) {
        float f = fb[o];
        #pragma unroll
        for (int w = 1; w < BLKS_PER_ROW; ++w) f = fmaxf(f, fb[w * 16 + o]);
        acc += fcw[cls * NCH + o] * f;
    }
    out[i] = acc;
}

extern "C" void kernel_launch(void* const* d_in, const int* in_sizes, int n_in,
                              void* d_out, int out_size, void* d_ws, size_t ws_size,
                              hipStream_t stream) {
    const int*   words = (const int*)  d_in[0];
    const float* emb   = (const float*)d_in[1];
    const float* w2    = (const float*)d_in[2];
    const float* b2    = (const float*)d_in[3];
    const float* w3    = (const float*)d_in[4];
    const float* b3    = (const float*)d_in[5];
    const float* w4    = (const float*)d_in[6];
    const float* b4    = (const float*)d_in[7];
    const float* w5    = (const float*)d_in[8];
    const float* b5    = (const float*)d_in[9];
    const float* fcw   = (const float*)d_in[10];
    const float* fcb   = (const float*)d_in[11];
    float* out = (float*)d_out;
    char*  ws  = (char*)d_ws;

    unsigned short* wsb  = (unsigned short*)ws;
    float* biasf = (float*)(ws + BIAS_OFF);
    float* feats = (float*)(ws + FEAT_OFF);

    hipLaunchKernelGGL(repack_w, dim3(40), dim3(256), 0, stream,
                       w2, b2, w3, b3, w4, b4, w5, b5, wsb, biasf);
    hipLaunchKernelGGL(cnn_mfma, dim3(NBLK), dim3(256), 0, stream,
                       words, emb, ws, feats);
    hipLaunchKernelGGL(fc_kernel, dim3((BATCH * NCLS + 255) / 256), dim3(256), 0, stream,
                       feats, fcw, fcb, out);
}